// Round 2
// baseline (29.183 us; speedup 1.0000x reference)
//
#include <hip/hip_runtime.h>
#include <hip/hip_bf16.h>

#define BS 32
#define NQ 300
#define NC 92
#define NT 50
#define Q_TOT (BS * NQ)   // 9600
#define T_TOT (BS * NT)   // 1600
#define QPB 8             // q-rows per block (9600 = 1200 * 8)
#define TPB 320           // threads per block = targets per block (1600 = 5 * 320)

// Fully fused: each block owns QPB query rows x TPB targets.
// Phase 1: the block's 5 waves compute softmax stats (rowmax, 1/sumexp) for the
//          8 rows in-block (wave w handles rows w, w+5). 5x grid redundancy in
//          grid.x is negligible (logits are L2-resident).
// Phase 2: identical fused cost math; stats come from LDS->registers.
__global__ __launch_bounds__(TPB) void fused_cost_kernel(
    const float* __restrict__ pred_logits,  // [Q_TOT, NC]
    const float* __restrict__ pred_boxes,   // [Q_TOT, 4] cxcywh
    const int*   __restrict__ tgt_labels,   // [T_TOT]
    const float* __restrict__ tgt_boxes,    // [T_TOT, 4] cxcywh
    float* __restrict__ out)                // [Q_TOT, T_TOT]
{
    __shared__ float2 s_stats[QPB];

    const int tid  = threadIdx.x;
    const int wid  = tid >> 6;
    const int lane = tid & 63;
    const int q0   = blockIdx.y * QPB;

    // ---- Phase 1: per-row softmax stats (wave per row) ----
    for (int r = wid; r < QPB; r += TPB / 64) {
        const float* rp = pred_logits + (size_t)(q0 + r) * NC;
        float x0 = (lane < NC)      ? rp[lane]      : -INFINITY;
        float x1 = (lane + 64 < NC) ? rp[lane + 64] : -INFINITY;

        float m = fmaxf(x0, x1);
        #pragma unroll
        for (int off = 1; off < 64; off <<= 1)
            m = fmaxf(m, __shfl_xor(m, off));

        float s = __expf(x0 - m) + __expf(x1 - m);   // exp(-inf - m) == 0
        #pragma unroll
        for (int off = 1; off < 64; off <<= 1)
            s += __shfl_xor(s, off);

        if (lane == 0)
            s_stats[r] = make_float2(m, 1.0f / s);
    }

    // ---- Target-side data: registers for the whole q-loop ----
    const int t = blockIdx.x * TPB + tid;
    const float4 tb = *reinterpret_cast<const float4*>(tgt_boxes + 4 * t); // cx cy w h
    const float tx0 = tb.x - 0.5f * tb.z, ty0 = tb.y - 0.5f * tb.w;
    const float tx1 = tb.x + 0.5f * tb.z, ty1 = tb.y + 0.5f * tb.w;
    const float tarea = tb.z * tb.w;
    const int lbl = tgt_labels[t];

    __syncthreads();

    float2 st[QPB];
    #pragma unroll
    for (int i = 0; i < QPB; ++i) st[i] = s_stats[i];

    // ---- Phase 2: fused cost ----
    #pragma unroll
    for (int i = 0; i < QPB; ++i) {
        const int q = q0 + i;
        const float4 qb = *reinterpret_cast<const float4*>(pred_boxes + 4 * q); // uniform -> s_load
        const float logit = pred_logits[(size_t)q * NC + lbl];
        const float prob  = __expf(logit - st[i].x) * st[i].y;

        // L1 cost in cxcywh space
        const float l1 = fabsf(qb.x - tb.x) + fabsf(qb.y - tb.y)
                       + fabsf(qb.z - tb.z) + fabsf(qb.w - tb.w);

        // GIoU in xyxy space
        const float qx0 = qb.x - 0.5f * qb.z, qy0 = qb.y - 0.5f * qb.w;
        const float qx1 = qb.x + 0.5f * qb.z, qy1 = qb.y + 0.5f * qb.w;
        const float qarea = qb.z * qb.w;

        const float ix0 = fmaxf(qx0, tx0), iy0 = fmaxf(qy0, ty0);
        const float ix1 = fminf(qx1, tx1), iy1 = fminf(qy1, ty1);
        const float iw = fmaxf(ix1 - ix0, 0.0f), ih = fmaxf(iy1 - iy0, 0.0f);
        const float inter = iw * ih;
        const float uni   = qarea + tarea - inter;

        // Enclosing box: always >= both boxes, w/h > 0 by construction -> no clamps.
        const float ex0 = fminf(qx0, tx0), ey0 = fminf(qy0, ty0);
        const float ex1 = fmaxf(qx1, tx1), ey1 = fmaxf(qy1, ty1);
        const float earea = (ex1 - ex0) * (ey1 - ey0);

        // giou = inter/uni - (earea - uni)/earea
        //      = (inter*earea - uni*earea + uni^2) * rcp(uni*earea)   (one rcp)
        const float ue  = uni * earea;
        const float r   = __builtin_amdgcn_rcpf(ue);
        float num = inter * earea - ue;
        num = fmaf(uni, uni, num);
        const float giou = num * r;

        // C = l1 - prob - giou
        __builtin_nontemporal_store(l1 - prob - giou, &out[(size_t)q * T_TOT + t]);
    }
}

extern "C" void kernel_launch(void* const* d_in, const int* in_sizes, int n_in,
                              void* d_out, int out_size, void* d_ws, size_t ws_size,
                              hipStream_t stream) {
    const float* pred_logits = (const float*)d_in[0]; // [32,300,92]
    const float* pred_boxes  = (const float*)d_in[1]; // [32,300,4]
    const int*   tgt_labels  = (const int*)d_in[2];   // [32,50]
    const float* tgt_boxes   = (const float*)d_in[3]; // [32,50,4]
    float* out = (float*)d_out;                       // [32,300,1600]

    dim3 grid(T_TOT / TPB, Q_TOT / QPB);              // (5, 1200)
    fused_cost_kernel<<<grid, TPB, 0, stream>>>(pred_logits, pred_boxes,
                                                tgt_labels, tgt_boxes, out);
}